// Round 4
// baseline (4292.389 us; speedup 1.0000x reference)
//
#include <hip/hip_runtime.h>

// Group VQ via bf16-MFMA filter + exact fp32 certify/fallback.
//   x [16,2,256,4000] fp32, cb [8,1024,64] fp32. token (b,g,t): x[b, g*64+dd, t].
// Pipeline:
//   k_init: zero worklist counter (ws is 0xAA-poisoned every call).
//   k_prep: cb -> bf16 copy; e2 (np-pairwise, exact) and e2p = e2+256.
//   k_mfma: per wave 16 tokens; C[16 tok x 16 codes] = A(tok,D) . B(D,code) via
//           2x mfma_f32_16x16x32_bf16. Track per-token packed top-2
//           (u32 = (score bits & ~0x3FF) | k : bit-min == (score,k) lexicographic,
//            score = e2p - 2*dot > 0 always since e2p = e2+256).
//           gap > DELTA -> certified, write idx. else append token to worklist.
//   k_fix:  per wave one hard token: verbatim R3 np-faithful exact argmin
//           (pairwise x2/e2 + 4-chain fma dot + (x2-2dot)+e2 + strict-< ).
//   k_out:  gather winning rows, write x_q and x_q_detach (coalesced along t).
// Certification: bf16 dot err std ~0.016 (64 rne-rounded products), DELTA=0.75
// is ~10-sigma + 0.06 packing slack -> wrong-certify prob ~1e-14. Hard tokens
// (~9%) are handled by the exact R3 pipeline, which benched absmax 0.0.

typedef short bf16x8 __attribute__((ext_vector_type(8)));
typedef float f32x4  __attribute__((ext_vector_type(4)));

constexpr int Tt = 4000, D = 64;
constexpr long long OUT_HALF = 16LL * 512LL * 4000LL;
constexpr float DELTA = 0.75f;

// ws layout (bytes)
constexpr size_t OFF_CNT = 0;
constexpr size_t OFF_E2  = 256;                      // f32[8192]
constexpr size_t OFF_E2P = OFF_E2  + 8192 * 4;       // f32[8192]
constexpr size_t OFF_CBH = OFF_E2P + 8192 * 4;       // bf16[8192*64] = 1 MB
constexpr size_t OFF_IDX = OFF_CBH + 8192 * 64 * 2;  // u32[128*4000]
constexpr size_t OFF_WL  = OFF_IDX + 512000 * 4;     // u32[512000]

static __device__ __forceinline__ short f2bf(float f) {   // rne float->bf16 bits
    unsigned u = __float_as_uint(f);
    return (short)((u + 0x7FFFu + ((u >> 16) & 1u)) >> 16);
}

__global__ void k_init(unsigned* cnt) { *cnt = 0u; }

__global__ __launch_bounds__(256)
void k_prep(const float* __restrict__ cb, short* __restrict__ cbh,
            float* __restrict__ e2, float* __restrict__ e2p)
{
    const int row = blockIdx.x * 256 + threadIdx.x;      // 0..8191 = g*1024+k
    const float* __restrict__ e = cb + (size_t)row * D;
    float r[8];
    #pragma unroll
    for (int j = 0; j < 8; ++j) {
        float p = e[j] * e[j];
        asm volatile("" : "+v"(p));
        r[j] = p;
    }
    #pragma unroll
    for (int i = 1; i < 8; ++i) {
        #pragma unroll
        for (int j = 0; j < 8; ++j) {
            float p = e[8 * i + j] * e[8 * i + j];
            asm volatile("" : "+v"(p));
            r[j] += p;
        }
    }
    const float s = ((r[0] + r[1]) + (r[2] + r[3])) + ((r[4] + r[5]) + (r[6] + r[7]));
    e2[row]  = s;
    e2p[row] = s + 256.0f;
    short* __restrict__ hr = cbh + (size_t)row * D;
    #pragma unroll
    for (int d = 0; d < D; ++d) hr[d] = f2bf(e[d]);
}

__global__ __launch_bounds__(256)
void k_mfma(const float* __restrict__ x, const short* __restrict__ cbh,
            const float* __restrict__ e2p, unsigned* __restrict__ idxarr,
            unsigned* __restrict__ wl, unsigned* __restrict__ cnt)
{
    __shared__ float e2p_lds[1024];
    const int pair = blockIdx.y;                 // b*8+g
    const int g = pair & 7, b = pair >> 3;
    for (int i = threadIdx.x; i < 1024; i += 256) e2p_lds[i] = e2p[g * 1024 + i];
    __syncthreads();

    const int wave = threadIdx.x >> 6, lane = threadIdx.x & 63;
    const int t0 = blockIdx.x * 64 + wave * 16;  // 16 tokens per wave
    if (t0 >= Tt) return;
    const int lnib = lane & 15, lhi = lane >> 4;

    // A fragments: row m = lane&15 (token), k = (lane>>4)*8 + j (D-slice)
    const float* __restrict__ xcol = x + ((size_t)(b * 512 + g * 64)) * Tt;
    int tl = t0 + lnib; if (tl > Tt - 1) tl = Tt - 1;   // clamp (results discarded)
    bf16x8 a0, a1;
    #pragma unroll
    for (int j = 0; j < 8; ++j) {
        a0[j] = f2bf(xcol[(size_t)(lhi * 8 + j) * Tt + tl]);
        a1[j] = f2bf(xcol[(size_t)(lhi * 8 + 32 + j) * Tt + tl]);
    }

    const short* __restrict__ cbg = cbh + (size_t)g * 1024 * D;
    unsigned m1[4] = {0xFFFFFFFFu, 0xFFFFFFFFu, 0xFFFFFFFFu, 0xFFFFFFFFu};
    unsigned m2[4] = {0xFFFFFFFFu, 0xFFFFFFFFu, 0xFFFFFFFFu, 0xFFFFFFFFu};

    for (int nt = 0; nt < 64; ++nt) {
        // B fragments: col n = lane&15 (code), k = (lane>>4)*8 + j
        const size_t brow = (size_t)(nt * 16 + lnib) * D + lhi * 8;
        bf16x8 b0 = *(const bf16x8*)(cbg + brow);
        bf16x8 b1 = *(const bf16x8*)(cbg + brow + 32);
        f32x4 acc = {0.f, 0.f, 0.f, 0.f};
        acc = __builtin_amdgcn_mfma_f32_16x16x32_bf16(a0, b0, acc, 0, 0, 0);
        acc = __builtin_amdgcn_mfma_f32_16x16x32_bf16(a1, b1, acc, 0, 0, 0);
        const float    e2v = e2p_lds[nt * 16 + lnib];
        const unsigned kc  = (unsigned)(nt * 16 + lnib);
        #pragma unroll
        for (int r = 0; r < 4; ++r) {           // C: row m=(lane>>4)*4+r, col=lane&15
            const float s = __builtin_fmaf(acc[r], -2.0f, e2v);   // >0 always
            const unsigned u  = (__float_as_uint(s) & 0xFFFFFC00u) | kc;
            const unsigned hi = m1[r] > u ? m1[r] : u;
            m1[r] = m1[r] < u ? m1[r] : u;
            m2[r] = m2[r] < hi ? m2[r] : hi;
        }
    }

    // top-2 merge across the 16 lanes holding each token's columns
    #pragma unroll
    for (int r = 0; r < 4; ++r) {
        #pragma unroll
        for (int off = 1; off < 16; off <<= 1) {
            const unsigned o1 = (unsigned)__shfl_xor((int)m1[r], off, 16);
            const unsigned o2 = (unsigned)__shfl_xor((int)m2[r], off, 16);
            const unsigned hi = m1[r] > o1 ? m1[r] : o1;
            m1[r] = m1[r] < o1 ? m1[r] : o1;
            const unsigned mn = m2[r] < o2 ? m2[r] : o2;
            m2[r] = mn < hi ? mn : hi;
        }
    }
    if (lnib == 0) {
        #pragma unroll
        for (int r = 0; r < 4; ++r) {
            const int t = t0 + lhi * 4 + r;
            if (t >= Tt) continue;
            const float f1 = __uint_as_float(m1[r] & 0xFFFFFC00u);
            const float f2 = __uint_as_float(m2[r] & 0xFFFFFC00u);
            if (f2 - f1 > DELTA) {
                idxarr[(unsigned)pair * Tt + t] = m1[r] & 1023u;  // certified
            } else {
                const unsigned slot = atomicAdd(cnt, 1u);
                wl[slot] = ((unsigned)pair << 12) | (unsigned)t;  // hard token
            }
        }
    }
}

__global__ __launch_bounds__(256)
void k_fix(const float* __restrict__ x, const float* __restrict__ cb,
           const float* __restrict__ e2, const unsigned* __restrict__ wl,
           const unsigned* __restrict__ cnt, unsigned* __restrict__ idxarr)
{
    const unsigned n  = *cnt;
    const int lane    = threadIdx.x & 63;
    const unsigned wid = (blockIdx.x * 256 + threadIdx.x) >> 6;
    const unsigned nw  = gridDim.x * 4;

    for (unsigned i = wid; i < n; i += nw) {
        const unsigned tok = wl[i];
        const int pair = tok >> 12, t = (int)(tok & 4095u);
        const int g = pair & 7, b = pair >> 3;
        const float* __restrict__ xcol = x + ((size_t)(b * 512 + g * 64)) * Tt + t;
        float xv[D];
        #pragma unroll
        for (int dd = 0; dd < D; ++dd) xv[dd] = xcol[(size_t)dd * Tt];
        // x2: np-pairwise (verbatim R3)
        float x2;
        {
            float r[8];
            #pragma unroll
            for (int j = 0; j < 8; ++j) {
                float p = xv[j] * xv[j];
                asm volatile("" : "+v"(p));
                r[j] = p;
            }
            #pragma unroll
            for (int i2 = 1; i2 < 8; ++i2) {
                #pragma unroll
                for (int j = 0; j < 8; ++j) {
                    float p = xv[8 * i2 + j] * xv[8 * i2 + j];
                    asm volatile("" : "+v"(p));
                    r[j] += p;
                }
            }
            x2 = ((r[0] + r[1]) + (r[2] + r[3])) + ((r[4] + r[5]) + (r[6] + r[7]));
        }
        const float* __restrict__ cbg = cb + (size_t)g * 1024 * D;
        const float* __restrict__ e2g = e2 + g * 1024;
        float best = 3.4e38f; int bi = 0;
        for (int j = 0; j < 16; ++j) {           // lane owns codes [lane*16, +16)
            const int k = lane * 16 + j;
            const float* __restrict__ e = cbg + (size_t)k * D;
            float l0 = 0.f, l1 = 0.f, l2 = 0.f, l3 = 0.f;
            #pragma unroll
            for (int dd = 0; dd < D; dd += 4) {
                l0 = __builtin_fmaf(e[dd + 0], xv[dd + 0], l0);
                l1 = __builtin_fmaf(e[dd + 1], xv[dd + 1], l1);
                l2 = __builtin_fmaf(e[dd + 2], xv[dd + 2], l2);
                l3 = __builtin_fmaf(e[dd + 3], xv[dd + 3], l3);
            }
            const float dot  = (l0 + l2) + (l1 + l3);
            const float dist = (x2 - 2.0f * dot) + e2g[k];
            if (dist < best) { best = dist; bi = k; }   // strict <, ascending k
        }
        #pragma unroll
        for (int off = 1; off < 64; off <<= 1) {
            const float ob = __shfl_xor(best, off);
            const int   oi = __shfl_xor(bi, off);
            if (ob < best || (ob == best && oi < bi)) { best = ob; bi = oi; }
        }
        if (lane == 0) idxarr[(unsigned)pair * Tt + t] = (unsigned)bi;
    }
}

__global__ __launch_bounds__(256)
void k_out(const float* __restrict__ x, const float* __restrict__ cb,
           const unsigned* __restrict__ idxarr, float* __restrict__ out)
{
    const int pair = blockIdx.y, g = pair & 7, b = pair >> 3;
    const int t = blockIdx.x * 256 + threadIdx.x;
    if (t >= Tt) return;
    const unsigned idx = idxarr[(unsigned)pair * Tt + t];
    const float* __restrict__ q  = cb + (size_t)g * 1024 * D + (size_t)idx * D;
    const size_t xbase = ((size_t)(b * 512 + g * 64)) * Tt + t;
    const float* __restrict__ xc = x + xbase;
    float* __restrict__ o1 = out + xbase;
    float* __restrict__ o2 = out + OUT_HALF + xbase;
    #pragma unroll
    for (int dd = 0; dd < D; ++dd) {
        const float qa = q[dd];
        const float xvv = xc[(size_t)dd * Tt];
        o1[(size_t)dd * Tt] = xvv + (qa - xvv);     // fl(x + fl(q-x))
        o2[(size_t)dd * Tt] = qa;
    }
}

extern "C" void kernel_launch(void* const* d_in, const int* in_sizes, int n_in,
                              void* d_out, int out_size, void* d_ws, size_t ws_size,
                              hipStream_t stream)
{
    const float* x  = (const float*)d_in[0];
    const float* cb = (const float*)d_in[1];
    float* out      = (float*)d_out;
    char* ws        = (char*)d_ws;

    unsigned* cnt    = (unsigned*)(ws + OFF_CNT);
    float*    e2     = (float*)   (ws + OFF_E2);
    float*    e2p    = (float*)   (ws + OFF_E2P);
    short*    cbh    = (short*)   (ws + OFF_CBH);
    unsigned* idxarr = (unsigned*)(ws + OFF_IDX);
    unsigned* wl     = (unsigned*)(ws + OFF_WL);

    hipLaunchKernelGGL(k_init, dim3(1), dim3(1), 0, stream, cnt);
    hipLaunchKernelGGL(k_prep, dim3(32), dim3(256), 0, stream, cb, cbh, e2, e2p);
    hipLaunchKernelGGL(k_mfma, dim3(63, 128), dim3(256), 0, stream,
                       x, cbh, e2p, idxarr, wl, cnt);
    hipLaunchKernelGGL(k_fix, dim3(512), dim3(256), 0, stream,
                       x, cb, e2, wl, cnt, idxarr);
    hipLaunchKernelGGL(k_out, dim3(16, 128), dim3(256), 0, stream,
                       x, cb, idxarr, out);
}

// Round 5
// 1146.043 us; speedup vs baseline: 3.7454x; 3.7454x over previous
//
#include <hip/hip_runtime.h>

// Group VQ via bf16-MFMA filter + exact fp32 certify/fallback. R5.
//   x [16,2,256,4000] fp32, cb [8,1024,64] fp32. token (b,g,t): x[b, g*64+dd, t].
// k_init: zero per-pair counters.
// k_prep: cb -> bf16; e2[k] = np-pairwise sum(e^2) (exact, matches np rounding).
// k_mfma: 256 tokens/block, 64/wave. Codebook chunked (128 codes = 16KB bf16)
//         into XOR-swizzled LDS shared by 4 waves (16x less L2 than R4).
//         A = bf16(-2x) (exact scale), C-init = e2+256 -> MFMA emits score
//         s = e2+256-2dot directly. Per-element top-2 via packed u32
//         (score&~1023 | k). gap > DELTA -> certified idx (u16); else append
//         token to per-pair worklist (u64 slot = [dist=~0:32][k=1023:10][t:12]).
// k_fix:  exact fallback, R3-proven numerics (np-pairwise x2/e2, 4-chain FMA,
//         (x2-2dot)+e2, strict <). Codes split 4-ways across blocks; thread
//         owns a token; codebook rows wave-uniform -> s_load (coalesced-free).
//         Exact merge via u64 atomicMin on (ordered-dist, k, t) lexicographic.
// k_fix3: unpack worklist winners into idx array.
// k_out:  gather q rows; write x_q = fl(x + fl(q-x)) and x_q_detach = q.

typedef short bf16x8 __attribute__((ext_vector_type(8)));
typedef float f32x4  __attribute__((ext_vector_type(4)));

constexpr int Tt = 4000, D = 64, K = 1024;
constexpr int CAP = 1536;                     // worklist capacity per pair (exp ~200)
constexpr float DELTA = 0.75f;
constexpr long long OUT_HALF = 16LL * 512LL * 4000LL;

// ws layout (bytes); total ~3.68 MB (< 5.0 MB proven in R4)
constexpr size_t OFF_CNT = 0;                 // u32[128]
constexpr size_t OFF_E2  = 512;               // f32[8192]
constexpr size_t OFF_CBH = 33280;             // bf16[8192*64] = 1 MB (128B-aligned)
constexpr size_t OFF_IDX = 1081856;           // u16[128*4000] = 1 MB
constexpr size_t OFF_WL  = 2105856;           // u64[128*1536] = 1.5 MB (8-aligned)

static __device__ __forceinline__ short f2bf(float f) {   // rne float->bf16 bits
    unsigned u = __float_as_uint(f);
    return (short)((u + 0x7FFFu + ((u >> 16) & 1u)) >> 16);
}

__global__ void k_init(unsigned* cnt) {
    if (threadIdx.x < 128) cnt[threadIdx.x] = 0u;
}

__global__ __launch_bounds__(256)
void k_prep(const float* __restrict__ cb, short* __restrict__ cbh,
            float* __restrict__ e2)
{
    const int row = blockIdx.x * 256 + threadIdx.x;      // 0..8191 = g*1024+k
    const float* __restrict__ e = cb + (size_t)row * D;
    float r[8];
    #pragma unroll
    for (int j = 0; j < 8; ++j) {
        float p = e[j] * e[j];
        asm volatile("" : "+v"(p));
        r[j] = p;
    }
    #pragma unroll
    for (int i = 1; i < 8; ++i) {
        #pragma unroll
        for (int j = 0; j < 8; ++j) {
            float p = e[8 * i + j] * e[8 * i + j];
            asm volatile("" : "+v"(p));
            r[j] += p;
        }
    }
    e2[row] = ((r[0] + r[1]) + (r[2] + r[3])) + ((r[4] + r[5]) + (r[6] + r[7]));
    unsigned* __restrict__ hr = (unsigned*)(cbh + (size_t)row * D);
    #pragma unroll
    for (int d = 0; d < 32; ++d) {
        const unsigned lo = (unsigned short)f2bf(e[2 * d]);
        const unsigned hi = (unsigned short)f2bf(e[2 * d + 1]);
        hr[d] = lo | (hi << 16);
    }
}

__global__ __launch_bounds__(256)
void k_mfma(const float* __restrict__ x, const short* __restrict__ cbh,
            const float* __restrict__ e2, unsigned short* __restrict__ idxarr,
            unsigned long long* __restrict__ wl, unsigned* __restrict__ cnt)
{
    __shared__ short cb_lds[128 * 64];       // 16KB chunk, XOR-swizzled
    __shared__ float e2_lds[K];              // e2 + 256 (keeps scores > 0)

    const int pair = blockIdx.y, g = pair & 7, b = pair >> 3;
    const int tid = threadIdx.x;
    for (int i = tid; i < K; i += 256) e2_lds[i] = e2[g * K + i] + 256.0f;

    const int wave = tid >> 6, lane = tid & 63, lnib = lane & 15, lhi = lane >> 4;
    const int t0w = blockIdx.x * 256 + wave * 64;

    // A fragments = bf16(-2x); row m = lane&15 (token), k = (lane>>4)*8+j
    const float* __restrict__ xcol = x + ((size_t)(b * 512 + g * 64)) * Tt;
    bf16x8 a[4][2];
    #pragma unroll
    for (int tt = 0; tt < 4; ++tt) {
        int tl = t0w + tt * 16 + lnib; if (tl > Tt - 1) tl = Tt - 1;  // clamp pad
        #pragma unroll
        for (int j = 0; j < 8; ++j) {
            a[tt][0][j] = f2bf(-2.0f * xcol[(size_t)(lhi * 8 + j) * Tt + tl]);
            a[tt][1][j] = f2bf(-2.0f * xcol[(size_t)(lhi * 8 + 32 + j) * Tt + tl]);
        }
    }

    const short* __restrict__ cbg = cbh + (size_t)g * K * D;
    unsigned m1[4][4], m2[4][4];
    #pragma unroll
    for (int tt = 0; tt < 4; ++tt)
        #pragma unroll
        for (int r = 0; r < 4; ++r) { m1[tt][r] = 0xFFFFFFFFu; m2[tt][r] = 0xFFFFFFFFu; }

    // swizzled LDS read bases: row = nt*16+lnib (row&7 == lnib&7, lane-const mask)
    const int sx   = (lnib & 7) << 4;
    const int rb   = lnib * 128 + lhi * 16;
    const int off0 = rb ^ sx;
    const int off1 = (rb + 64) ^ sx;
    const char* lds_bytes = (const char*)cb_lds;

    for (int c = 0; c < 8; ++c) {
        __syncthreads();                     // previous chunk's reads done
        {   // stage 16KB chunk: 4 x 16B per thread, swizzle on write
            const char* src = (const char*)(cbg + c * 128 * D);
            #pragma unroll
            for (int it = 0; it < 4; ++it) {
                const int L = it * 4096 + tid * 16;
                const int P = L ^ (((L >> 7) & 7) << 4);
                *(uint4*)((char*)cb_lds + P) = *(const uint4*)(src + L);
            }
        }
        __syncthreads();
        const int kbase = c * 128 + lnib;
        #pragma unroll
        for (int nt = 0; nt < 8; ++nt) {
            const bf16x8 b0 = *(const bf16x8*)(lds_bytes + off0 + nt * 2048);
            const bf16x8 b1 = *(const bf16x8*)(lds_bytes + off1 + nt * 2048);
            const float    e2v = e2_lds[kbase + nt * 16];
            const unsigned kc  = (unsigned)(kbase + nt * 16);
            #pragma unroll
            for (int tt = 0; tt < 4; ++tt) {
                f32x4 acc = {e2v, e2v, e2v, e2v};      // C-init = e2+256
                acc = __builtin_amdgcn_mfma_f32_16x16x32_bf16(a[tt][0], b0, acc, 0, 0, 0);
                acc = __builtin_amdgcn_mfma_f32_16x16x32_bf16(a[tt][1], b1, acc, 0, 0, 0);
                #pragma unroll
                for (int r = 0; r < 4; ++r) {          // s = e2+256-2dot, >0
                    const unsigned u  = (__float_as_uint(acc[r]) & 0xFFFFFC00u) | kc;
                    const unsigned hi = m1[tt][r] > u ? m1[tt][r] : u;
                    m1[tt][r] = m1[tt][r] < u ? m1[tt][r] : u;
                    m2[tt][r] = m2[tt][r] < hi ? m2[tt][r] : hi;
                }
            }
        }
    }

    // top-2 merge across the 16 lanes holding each token's columns, then emit
    #pragma unroll
    for (int tt = 0; tt < 4; ++tt) {
        #pragma unroll
        for (int r = 0; r < 4; ++r) {
            #pragma unroll
            for (int off = 1; off < 16; off <<= 1) {
                const unsigned o1 = (unsigned)__shfl_xor((int)m1[tt][r], off, 16);
                const unsigned o2 = (unsigned)__shfl_xor((int)m2[tt][r], off, 16);
                const unsigned hi = m1[tt][r] > o1 ? m1[tt][r] : o1;
                m1[tt][r] = m1[tt][r] < o1 ? m1[tt][r] : o1;
                const unsigned mn = m2[tt][r] < o2 ? m2[tt][r] : o2;
                m2[tt][r] = mn < hi ? mn : hi;
            }
            if (lnib == 0) {
                const int t = t0w + tt * 16 + lhi * 4 + r;   // C row -> token
                if (t < Tt) {
                    const float f1 = __uint_as_float(m1[tt][r] & 0xFFFFFC00u);
                    const float f2 = __uint_as_float(m2[tt][r] & 0xFFFFFC00u);
                    const unsigned kwin = m1[tt][r] & 1023u;
                    if (f2 - f1 > DELTA) {
                        idxarr[(unsigned)pair * Tt + t] = (unsigned short)kwin;
                    } else {
                        const unsigned slot = atomicAdd(cnt + pair, 1u);
                        if (slot < (unsigned)CAP) {
                            wl[(size_t)pair * CAP + slot] =
                                (0xFFFFFFFFULL << 22) | (1023ULL << 12)
                                | (unsigned long long)(unsigned)t;
                        } else {   // graceful overflow (expected never: n~200)
                            idxarr[(unsigned)pair * Tt + t] = (unsigned short)kwin;
                        }
                    }
                }
            }
        }
    }
}

__global__ __launch_bounds__(256)
void k_fix(const float* __restrict__ x, const float* __restrict__ cb,
           const float* __restrict__ e2, const unsigned* __restrict__ cnt,
           unsigned long long* __restrict__ wl)
{
    const int pair = blockIdx.y, g = pair & 7, b = pair >> 3;
    const int q = blockIdx.x;                 // code quarter: [q*256, q*256+256)
    unsigned n = cnt[pair]; if (n > (unsigned)CAP) n = CAP;
    const float* __restrict__ cbg  = cb + (size_t)g * K * D;
    const float* __restrict__ e2g  = e2 + g * K;
    const float* __restrict__ xcol = x + ((size_t)(b * 512 + g * 64)) * Tt;

    for (unsigned i = threadIdx.x; i < n; i += 256) {
        unsigned long long* slot = &wl[(size_t)pair * CAP + i];
        const int t = (int)(*slot & 4095u);
        float xv[D];
        #pragma unroll
        for (int dd = 0; dd < D; ++dd) xv[dd] = xcol[(size_t)dd * Tt + t];
        // x2: np-pairwise (verbatim R3)
        float x2;
        {
            float r[8];
            #pragma unroll
            for (int j = 0; j < 8; ++j) {
                float p = xv[j] * xv[j];
                asm volatile("" : "+v"(p));
                r[j] = p;
            }
            #pragma unroll
            for (int i2 = 1; i2 < 8; ++i2) {
                #pragma unroll
                for (int j = 0; j < 8; ++j) {
                    float p = xv[8 * i2 + j] * xv[8 * i2 + j];
                    asm volatile("" : "+v"(p));
                    r[j] += p;
                }
            }
            x2 = ((r[0] + r[1]) + (r[2] + r[3])) + ((r[4] + r[5]) + (r[6] + r[7]));
        }
        float best = 3.4e38f; int bk = q * 256;
        for (int j = 0; j < 256; ++j) {       // k ascending -> first-index ties
            const int k = q * 256 + j;
            const float* __restrict__ e = cbg + (size_t)k * D;  // uniform -> s_load
            float l0 = 0.f, l1 = 0.f, l2 = 0.f, l3 = 0.f;
            #pragma unroll
            for (int dd = 0; dd < D; dd += 4) {
                l0 = __builtin_fmaf(e[dd + 0], xv[dd + 0], l0);
                l1 = __builtin_fmaf(e[dd + 1], xv[dd + 1], l1);
                l2 = __builtin_fmaf(e[dd + 2], xv[dd + 2], l2);
                l3 = __builtin_fmaf(e[dd + 3], xv[dd + 3], l3);
            }
            const float dot  = (l0 + l2) + (l1 + l3);
            const float dist = (x2 - 2.0f * dot) + e2g[k];
            if (dist < best) { best = dist; bk = k; }
        }
        unsigned ob = __float_as_uint(best);
        ob ^= (unsigned)((int)ob >> 31) | 0x80000000u;     // total-order map
        atomicMin(slot, ((unsigned long long)ob << 22)
                        | ((unsigned long long)(unsigned)bk << 12)
                        | (unsigned long long)(unsigned)t);
    }
}

__global__ void k_fix3(const unsigned* __restrict__ cnt,
                       const unsigned long long* __restrict__ wl,
                       unsigned short* __restrict__ idxarr)
{
    const int pair = blockIdx.x;
    unsigned n = cnt[pair]; if (n > (unsigned)CAP) n = CAP;
    for (unsigned i = threadIdx.x; i < n; i += 256) {
        const unsigned long long e = wl[(size_t)pair * CAP + i];
        idxarr[(unsigned)pair * Tt + (unsigned)(e & 4095u)] =
            (unsigned short)((e >> 12) & 1023u);
    }
}

__global__ __launch_bounds__(256)
void k_out(const float* __restrict__ x, const float* __restrict__ cb,
           const unsigned short* __restrict__ idxarr, float* __restrict__ out)
{
    const int pair = blockIdx.y, g = pair & 7, b = pair >> 3;
    const int t = blockIdx.x * 256 + threadIdx.x;
    if (t >= Tt) return;
    const unsigned idx = idxarr[(unsigned)pair * Tt + t];
    const float* __restrict__ q  = cb + (size_t)g * K * D + (size_t)idx * D;
    const size_t xbase = ((size_t)(b * 512 + g * 64)) * Tt + t;
    const float* __restrict__ xc = x + xbase;
    float* __restrict__ o1 = out + xbase;
    float* __restrict__ o2 = out + OUT_HALF + xbase;
    #pragma unroll
    for (int dd = 0; dd < D; ++dd) {
        const float qa  = q[dd];
        const float xvv = xc[(size_t)dd * Tt];
        o1[(size_t)dd * Tt] = xvv + (qa - xvv);   // fl(x + fl(q-x))
        o2[(size_t)dd * Tt] = qa;
    }
}

extern "C" void kernel_launch(void* const* d_in, const int* in_sizes, int n_in,
                              void* d_out, int out_size, void* d_ws, size_t ws_size,
                              hipStream_t stream)
{
    const float* x  = (const float*)d_in[0];
    const float* cb = (const float*)d_in[1];
    float* out      = (float*)d_out;
    char* ws        = (char*)d_ws;

    unsigned*           cnt    = (unsigned*)(ws + OFF_CNT);
    float*              e2     = (float*)   (ws + OFF_E2);
    short*              cbh    = (short*)   (ws + OFF_CBH);
    unsigned short*     idxarr = (unsigned short*)(ws + OFF_IDX);
    unsigned long long* wl     = (unsigned long long*)(ws + OFF_WL);

    hipLaunchKernelGGL(k_init, dim3(1), dim3(128), 0, stream, cnt);
    hipLaunchKernelGGL(k_prep, dim3(32), dim3(256), 0, stream, cb, cbh, e2);
    hipLaunchKernelGGL(k_mfma, dim3(16, 128), dim3(256), 0, stream,
                       x, cbh, e2, idxarr, wl, cnt);
    hipLaunchKernelGGL(k_fix, dim3(4, 128), dim3(256), 0, stream,
                       x, cb, e2, cnt, wl);
    hipLaunchKernelGGL(k_fix3, dim3(128), dim3(256), 0, stream, cnt, wl, idxarr);
    hipLaunchKernelGGL(k_out, dim3(16, 128), dim3(256), 0, stream,
                       x, cb, idxarr, out);
}